// Round 10
// baseline (155.692 us; speedup 1.0000x reference)
//
#include <hip/hip_runtime.h>
#include <hip/hip_bf16.h>

#define B_ROWS 8192
#define DIM 256
#define C_CLS 5994
#define N_CHUNK 188       // 6016 / 32
#define NSPL 16
#define H_HALF 4096
#define SCALE_F 30.0f
#define MAXL 30.0f
#define EXPC 43.2808512266689f   // 30*log2(e):  exp(30x-30) = exp2(EXPC*x - EXPC)

#if defined(__has_builtin)
#if __has_builtin(__builtin_amdgcn_exp2f)
#define EXP2(x) __builtin_amdgcn_exp2f(x)
#endif
#endif
#ifndef EXP2
#define EXP2(x) exp2f(x)
#endif

typedef _Float16 half8 __attribute__((ext_vector_type(8)));
typedef float f32x16 __attribute__((ext_vector_type(16)));

// ---------------- pack: norms + blocked f16 layouts + accum zero ---------
// Blocked layout per 32-row tile (16 KB): half_off = tile*8192 + k*512 + lh*256 + l31*8 + idx
// A wave's MFMA fragment load (fixed k) is lane-linear -> one contiguous 1 KB load.
__global__ __launch_bounds__(256)
void k_pack(const float* __restrict__ emb, const float* __restrict__ W,
            _Float16* __restrict__ en_blk, _Float16* __restrict__ wn_blk,
            float* __restrict__ rne, float* __restrict__ rnw,
            float* __restrict__ accum) {
  __shared__ float ssm[256];
  __shared__ float rnl[32];
  const int b = blockIdx.x;
  const int t = threadIdx.x;
  if (b == 0 && t < 8) accum[t] = 0.f;   // accum[0..3] + counter(+pad), zeroed every call
  const bool isW = b >= (B_ROWS/32);
  const int tile = isW ? b - (B_ROWS/32) : b;
  const int l31 = t & 31;
  const int row = tile*32 + l31;
  const float* __restrict__ src = isW ? W : emb;
  const bool rv = (!isW) || (row < C_CLS);

  float v[4][8];
  float ss = 0.f;
  #pragma unroll
  for (int i=0;i<4;i++) {
    const int d0 = ((t>>6) + i*4)*16 + ((t>>5)&1)*8;
    if (rv) {
      float4 x0 = *(const float4*)(src + (size_t)row*DIM + d0);
      float4 x1 = *(const float4*)(src + (size_t)row*DIM + d0 + 4);
      v[i][0]=x0.x; v[i][1]=x0.y; v[i][2]=x0.z; v[i][3]=x0.w;
      v[i][4]=x1.x; v[i][5]=x1.y; v[i][6]=x1.z; v[i][7]=x1.w;
      ss += x0.x*x0.x + x0.y*x0.y + x0.z*x0.z + x0.w*x0.w
          + x1.x*x1.x + x1.y*x1.y + x1.z*x1.z + x1.w*x1.w;
    } else {
      #pragma unroll
      for (int j=0;j<8;j++) v[i][j] = 0.f;
    }
  }
  ssm[t] = ss;
  __syncthreads();
  if (t < 32) {
    float s = 0.f;
    #pragma unroll
    for (int j=0;j<8;j++) s += ssm[t + j*32];
    float rn = 1.0f/(sqrtf(s) + 1e-12f);
    rnl[t] = rn;
    int rw = tile*32 + t;
    if (!isW) rne[rw] = rn;
    else if (rw < C_CLS) rnw[rw] = rn;
  }
  __syncthreads();
  const float rn = rnl[l31];
  _Float16* __restrict__ dst = (isW ? wn_blk : en_blk) + (size_t)tile*8192;
  #pragma unroll
  for (int i=0;i<4;i++) {
    half8 h;
    #pragma unroll
    for (int j=0;j<8;j++) h[j] = (_Float16)(v[i][j]*rn);
    *(half8*)(dst + t*8 + i*2048) = h;   // coalesced 16B stores
  }
}

// ---------------- main fused GEMM + online softmax-stats ----------------
// grid = 64 panels x 16 splits = 1024 blocks (4/CU -> 4 waves/SIMD);
// block = 256 (4 waves x 32-row tile). Barrier-free; B register-double-
// buffered (half-chunks); branch-free main loop (peeled last iteration).
__global__ __launch_bounds__(256, 4)
void k_logits(const _Float16* __restrict__ en_blk, const _Float16* __restrict__ wn_blk,
              float* __restrict__ psum, unsigned* __restrict__ pkey) {
  const int split = blockIdx.x & (NSPL-1);
  const int panel = blockIdx.x / NSPL;
  const int wid  = threadIdx.x >> 6;
  const int lane = threadIdx.x & 63;
  const int l31  = lane & 31;
  const int lh   = lane >> 5;
  const int tile = panel*4 + wid;

  // A fragments: 16 contiguous 1 KB wave-loads, resident all loop
  half8 a[16];
  const _Float16* ab = en_blk + (size_t)tile*8192 + lane*8;
  #pragma unroll
  for (int k=0;k<16;k++) a[k] = *(const half8*)(ab + k*512);

  float ssum[16]; unsigned key[16];
  #pragma unroll
  for (int r=0;r<16;r++){ ssum[r]=0.f; key[r]=0u; }

  const int nit = (N_CHUNK - split + NSPL - 1) / NSPL;   // 12 or 11
  const _Float16* p = wn_blk + (size_t)split*8192 + lane*8;
  const ptrdiff_t STEP = (ptrdiff_t)NSPL*8192;

  half8 b0[8], b1[8];
  #pragma unroll
  for (int k=0;k<8;k++) b0[k] = *(const half8*)(p + k*512);
  #pragma unroll
  for (int k=0;k<8;k++) b1[k] = *(const half8*)(p + (k+8)*512);

  unsigned colu = (unsigned)(split*32 + l31);
  for (int it = 0; it < nit-1; ++it) {
    const _Float16* pn = p + STEP;
    f32x16 acc = {};
    #pragma unroll
    for (int k=0;k<8;k++)
      acc = __builtin_amdgcn_mfma_f32_32x32x16_f16(a[k], b0[k], acc, 0,0,0);
    #pragma unroll
    for (int k=0;k<8;k++) b0[k] = *(const half8*)(pn + k*512);
    #pragma unroll
    for (int k=0;k<8;k++)
      acc = __builtin_amdgcn_mfma_f32_32x32x16_f16(a[k+8], b1[k], acc, 0,0,0);
    #pragma unroll
    for (int k=0;k<8;k++) b1[k] = *(const half8*)(pn + (k+8)*512);
    // epilogue: pad cols are zero rows -> x=0 -> exp2(-43.3)~1e-13, negligible
    #pragma unroll
    for (int r=0;r<16;r++) {
      float x = acc[r];                       // cosine in [-1,1]
      ssum[r] += EXP2(fmaf(x, EXPC, -EXPC));  // single v_exp_f32
      unsigned ky = (__float_as_uint(x + 2.0f) & 0xFFFFE000u) | colu;  // x+2>0: monotone
      key[r] = ky > key[r] ? ky : key[r];
    }
    colu += NSPL*32;
    p = pn;
  }
  { // last chunk, no prefetch
    f32x16 acc = {};
    #pragma unroll
    for (int k=0;k<8;k++)
      acc = __builtin_amdgcn_mfma_f32_32x32x16_f16(a[k], b0[k], acc, 0,0,0);
    #pragma unroll
    for (int k=0;k<8;k++)
      acc = __builtin_amdgcn_mfma_f32_32x32x16_f16(a[k+8], b1[k], acc, 0,0,0);
    #pragma unroll
    for (int r=0;r<16;r++) {
      float x = acc[r];
      ssum[r] += EXP2(fmaf(x, EXPC, -EXPC));
      unsigned ky = (__float_as_uint(x + 2.0f) & 0xFFFFE000u) | colu;
      key[r] = ky > key[r] ? ky : key[r];
    }
  }

  // reduce across the 32 lanes (cols); offsets 1..16 stay within each half
  #pragma unroll
  for (int off=1; off<32; off<<=1) {
    #pragma unroll
    for (int r=0;r<16;r++) {
      ssum[r] += __shfl_xor(ssum[r], off);
      unsigned o = __shfl_xor(key[r], off);
      key[r] = o > key[r] ? o : key[r];
    }
  }
  if (l31 == 0) {
    const int rowbase = tile*32;
    #pragma unroll
    for (int r=0;r<16;r++) {
      int row = rowbase + (r&3) + 8*(r>>2) + 4*lh;
      psum[split*B_ROWS + row] = ssum[r];
      pkey[split*B_ROWS + row] = key[r];
    }
  }
}

// ---------------- tail: das + merge + finalize (completion counter) ------
__global__ __launch_bounds__(256)
void k_tail(const float* __restrict__ emb, const float* __restrict__ W,
            const int* __restrict__ y, const int* __restrict__ y_d,
            const float* __restrict__ rne, const float* __restrict__ rnw,
            const float* __restrict__ psum, const unsigned* __restrict__ pkey,
            float* __restrict__ accum, float* __restrict__ out) {
  __shared__ float s0[4], s1[4];
  const int wid = threadIdx.x >> 6, lane = threadIdx.x & 63;
  if (blockIdx.x < 128) {
    // ----- merge: per-row exact y-logit + combine partials -----
    float lacc = 0.f, cacc = 0.f;
    for (int row = blockIdx.x*4 + wid; row < B_ROWS; row += 512) {
      const int yc = y[row];
      float4 e = *(const float4*)(emb + (size_t)row*DIM + lane*4);
      float4 w = *(const float4*)(W + (size_t)yc*DIM + lane*4);
      float d = e.x*w.x + e.y*w.y + e.z*w.z + e.w*w.w;
      #pragma unroll
      for (int off=1; off<64; off<<=1) d += __shfl_xor(d, off);
      float S = 0.f; unsigned km = 0u;
      if (lane < NSPL) {
        S = psum[lane*B_ROWS + row];
        km = pkey[lane*B_ROWS + row];
      }
      #pragma unroll
      for (int off=1; off<NSPL; off<<=1) {
        S += __shfl_xor(S, off);
        unsigned o = __shfl_xor(km, off);
        if (o > km) km = o;
      }
      if (lane == 0) {
        float ly = SCALE_F * d * rne[row] * rnw[yc];
        lacc += MAXL + logf(S) - ly;
        cacc += ((km & 0x1FFFu) == (unsigned)yc) ? 1.f : 0.f;
      }
    }
    if (lane == 0) { s0[wid] = lacc; s1[wid] = cacc; }
    __syncthreads();
    if (threadIdx.x == 0) {
      atomicAdd(&accum[0], s0[0]+s0[1]+s0[2]+s0[3]);
      atomicAdd(&accum[1], s1[0]+s1[1]+s1[2]+s1[3]);
    }
  } else {
    // ----- das: contrastive pair distances (f32, from raw emb) -----
    float a2 = 0.f, a3 = 0.f;
    for (int i = (blockIdx.x-128)*4 + wid; i < H_HALF; i += 256) {
      const int j = (i+1) & (H_HALF-1);
      const int di = y_d[i], dj = y_d[j], dih = y_d[i + H_HALF];
      float4 z = {0.f,0.f,0.f,0.f};
      float4 mi = (di==0)  ? *(const float4*)(emb + (size_t)i*DIM + lane*4) : z;
      float4 mj = (dj==0)  ? *(const float4*)(emb + (size_t)j*DIM + lane*4) : z;
      float4 ti = (dih!=0) ? *(const float4*)(emb + (size_t)(i+H_HALF)*DIM + lane*4)
                           : ((di!=0) ? *(const float4*)(emb + (size_t)i*DIM + lane*4) : z);
      float px = mi.x-mj.x, py = mi.y-mj.y, pz = mi.z-mj.z, pw = mi.w-mj.w;
      float nx = mi.x-ti.x, ny = mi.y-ti.y, nz = mi.z-ti.z, nw = mi.w-ti.w;
      float sp = px*px+py*py+pz*pz+pw*pw;
      float sn = nx*nx+ny*ny+nz*nz+nw*nw;
      #pragma unroll
      for (int off=1; off<64; off<<=1) { sp += __shfl_xor(sp, off); sn += __shfl_xor(sn, off); }
      if (lane == 0) {
        float dp = sqrtf(sp), dn = sqrtf(sn);
        float m = fmaxf(2.0f - dp, 0.f);
        a2 += m*m + dn*dn;
        a3 += dp + dn;
      }
    }
    if (lane == 0) { s0[wid] = a2; s1[wid] = a3; }
    __syncthreads();
    if (threadIdx.x == 0) {
      atomicAdd(&accum[2], s0[0]+s0[1]+s0[2]+s0[3]);
      atomicAdd(&accum[3], s1[0]+s1[1]+s1[2]+s1[3]);
    }
  }
  // ----- finalize: last block to finish writes the 4 outputs -----
  if (threadIdx.x == 0) {
    __threadfence();                                   // publish accum adds
    unsigned* cnt = (unsigned*)(accum + 4);
    unsigned done = atomicAdd(cnt, 1u);
    if (done == 191u) {                                // last of 192 blocks
      float v0 = atomicAdd(&accum[0], 0.f);            // coherent reads
      float v1 = atomicAdd(&accum[1], 0.f);
      float v2 = atomicAdd(&accum[2], 0.f);
      float v3 = atomicAdd(&accum[3], 0.f);
      out[0] = v0 * (1.0f/B_ROWS);  // loss_c
      out[1] = v2 * (1.0f/B_ROWS);  // das_loss
      out[2] = v1 * (1.0f/B_ROWS);  // acc
      out[3] = v3 * (1.0f/B_ROWS);  // das_dist_mean
    }
  }
}

extern "C" void kernel_launch(void* const* d_in, const int* in_sizes, int n_in,
                              void* d_out, int out_size, void* d_ws, size_t ws_size,
                              hipStream_t stream) {
  const float* emb = (const float*)d_in[0];
  const float* W   = (const float*)d_in[1];
  const int*   y   = (const int*)d_in[2];
  const int*   y_d = (const int*)d_in[3];

  char* ws = (char*)d_ws;
  const size_t EN_OFF   = 0;                                  // 256 tiles * 16 KB = 4,194,304
  const size_t WN_OFF   = EN_OFF  + (size_t)256*16384;        // 188 tiles * 16 KB = 3,080,192
  const size_t RNE_OFF  = WN_OFF  + (size_t)N_CHUNK*16384;    // 32,768
  const size_t RNW_OFF  = RNE_OFF + (size_t)B_ROWS*4;         // 24,064 (6016 floats)
  const size_t PSUM_OFF = RNW_OFF + 24064;                    // 16*8192*4 = 524,288
  const size_t PKEY_OFF = PSUM_OFF + (size_t)NSPL*B_ROWS*4;   // 16*8192*4 = 524,288
  const size_t ACC_OFF  = PKEY_OFF + (size_t)NSPL*B_ROWS*4;   // 32 (4 floats + cnt + pad)

  _Float16* en_blk = (_Float16*)(ws + EN_OFF);
  _Float16* wn_blk = (_Float16*)(ws + WN_OFF);
  float*    rne   = (float*)(ws + RNE_OFF);
  float*    rnw   = (float*)(ws + RNW_OFF);
  float*    psum  = (float*)(ws + PSUM_OFF);
  unsigned* pkey  = (unsigned*)(ws + PKEY_OFF);
  float*    accum = (float*)(ws + ACC_OFF);

  k_pack<<<B_ROWS/32 + N_CHUNK, 256, 0, stream>>>(emb, W, en_blk, wn_blk, rne, rnw, accum);
  k_logits<<<64*NSPL, 256, 0, stream>>>(en_blk, wn_blk, psum, pkey);
  k_tail<<<192, 256, 0, stream>>>(emb, W, y, y_d, rne, rnw, psum, pkey, accum, (float*)d_out);
}

// Round 11
// 77.773 us; speedup vs baseline: 2.0019x; 2.0019x over previous
//
#include <hip/hip_runtime.h>
#include <hip/hip_bf16.h>

#define B_ROWS 8192
#define DIM 256
#define C_CLS 5994
#define N_CHUNK 188       // 6016 / 32
#define NSPL 16
#define H_HALF 4096
#define SCALE_F 30.0f
#define MAXL 30.0f
#define EXPC 43.2808512266689f   // 30*log2(e):  exp(30x-30) = exp2(EXPC*x - EXPC)

#if defined(__has_builtin)
#if __has_builtin(__builtin_amdgcn_exp2f)
#define EXP2(x) __builtin_amdgcn_exp2f(x)
#endif
#endif
#ifndef EXP2
#define EXP2(x) exp2f(x)
#endif

typedef _Float16 half8 __attribute__((ext_vector_type(8)));
typedef float f32x16 __attribute__((ext_vector_type(16)));

// ---------------- pack: norms + blocked f16 layouts + accum zero ---------
// Blocked layout per 32-row tile (16 KB): half_off = tile*8192 + k*512 + lh*256 + l31*8 + idx
// A wave's MFMA fragment load (fixed k) is lane-linear -> one contiguous 1 KB load.
__global__ __launch_bounds__(256)
void k_pack(const float* __restrict__ emb, const float* __restrict__ W,
            _Float16* __restrict__ en_blk, _Float16* __restrict__ wn_blk,
            float* __restrict__ rne, float* __restrict__ rnw,
            float* __restrict__ accum) {
  __shared__ float ssm[256];
  __shared__ float rnl[32];
  const int b = blockIdx.x;
  const int t = threadIdx.x;
  if (b == 0 && t < 8) accum[t] = 0.f;   // accum[0..3] + counter(+pad), zeroed every call
  const bool isW = b >= (B_ROWS/32);
  const int tile = isW ? b - (B_ROWS/32) : b;
  const int l31 = t & 31;
  const int row = tile*32 + l31;
  const float* __restrict__ src = isW ? W : emb;
  const bool rv = (!isW) || (row < C_CLS);

  float v[4][8];
  float ss = 0.f;
  #pragma unroll
  for (int i=0;i<4;i++) {
    const int d0 = ((t>>6) + i*4)*16 + ((t>>5)&1)*8;
    if (rv) {
      float4 x0 = *(const float4*)(src + (size_t)row*DIM + d0);
      float4 x1 = *(const float4*)(src + (size_t)row*DIM + d0 + 4);
      v[i][0]=x0.x; v[i][1]=x0.y; v[i][2]=x0.z; v[i][3]=x0.w;
      v[i][4]=x1.x; v[i][5]=x1.y; v[i][6]=x1.z; v[i][7]=x1.w;
      ss += x0.x*x0.x + x0.y*x0.y + x0.z*x0.z + x0.w*x0.w
          + x1.x*x1.x + x1.y*x1.y + x1.z*x1.z + x1.w*x1.w;
    } else {
      #pragma unroll
      for (int j=0;j<8;j++) v[i][j] = 0.f;
    }
  }
  ssm[t] = ss;
  __syncthreads();
  if (t < 32) {
    float s = 0.f;
    #pragma unroll
    for (int j=0;j<8;j++) s += ssm[t + j*32];
    float rn = 1.0f/(sqrtf(s) + 1e-12f);
    rnl[t] = rn;
    int rw = tile*32 + t;
    if (!isW) rne[rw] = rn;
    else if (rw < C_CLS) rnw[rw] = rn;
  }
  __syncthreads();
  const float rn = rnl[l31];
  _Float16* __restrict__ dst = (isW ? wn_blk : en_blk) + (size_t)tile*8192;
  #pragma unroll
  for (int i=0;i<4;i++) {
    half8 h;
    #pragma unroll
    for (int j=0;j<8;j++) h[j] = (_Float16)(v[i][j]*rn);
    *(half8*)(dst + t*8 + i*2048) = h;   // coalesced 16B stores
  }
}

// ---------------- main fused GEMM + online softmax-stats ----------------
// grid = 64 panels x 16 splits = 1024 blocks (4/CU); block = 256 (4 waves).
// launch_bounds min-waves=2 -> VGPR cap 256; kernel uses ~104 -> 4 waves/SIMD
// achievable (512/104 = 4.9), grid now supplies them. Barrier-free; B
// register-double-buffered (half-chunks); peeled last iteration.
__global__ __launch_bounds__(256, 2)
void k_logits(const _Float16* __restrict__ en_blk, const _Float16* __restrict__ wn_blk,
              float* __restrict__ psum, unsigned* __restrict__ pkey) {
  const int split = blockIdx.x & (NSPL-1);
  const int panel = blockIdx.x / NSPL;
  const int wid  = threadIdx.x >> 6;
  const int lane = threadIdx.x & 63;
  const int l31  = lane & 31;
  const int lh   = lane >> 5;
  const int tile = panel*4 + wid;

  // A fragments: 16 contiguous 1 KB wave-loads, resident all loop
  half8 a[16];
  const _Float16* ab = en_blk + (size_t)tile*8192 + lane*8;
  #pragma unroll
  for (int k=0;k<16;k++) a[k] = *(const half8*)(ab + k*512);

  float ssum[16]; unsigned key[16];
  #pragma unroll
  for (int r=0;r<16;r++){ ssum[r]=0.f; key[r]=0u; }

  const int nit = (N_CHUNK - split + NSPL - 1) / NSPL;   // 12 or 11
  const _Float16* p = wn_blk + (size_t)split*8192 + lane*8;
  const ptrdiff_t STEP = (ptrdiff_t)NSPL*8192;

  half8 b0[8], b1[8];
  #pragma unroll
  for (int k=0;k<8;k++) b0[k] = *(const half8*)(p + k*512);
  #pragma unroll
  for (int k=0;k<8;k++) b1[k] = *(const half8*)(p + (k+8)*512);

  unsigned colu = (unsigned)(split*32 + l31);
  for (int it = 0; it < nit-1; ++it) {
    const _Float16* pn = p + STEP;
    f32x16 acc = {};
    #pragma unroll
    for (int k=0;k<8;k++)
      acc = __builtin_amdgcn_mfma_f32_32x32x16_f16(a[k], b0[k], acc, 0,0,0);
    #pragma unroll
    for (int k=0;k<8;k++) b0[k] = *(const half8*)(pn + k*512);
    #pragma unroll
    for (int k=0;k<8;k++)
      acc = __builtin_amdgcn_mfma_f32_32x32x16_f16(a[k+8], b1[k], acc, 0,0,0);
    #pragma unroll
    for (int k=0;k<8;k++) b1[k] = *(const half8*)(pn + (k+8)*512);
    // epilogue: pad cols are zero rows -> x=0 -> exp2(-43.3)~1e-13, negligible
    #pragma unroll
    for (int r=0;r<16;r++) {
      float x = acc[r];                       // cosine in [-1,1]
      ssum[r] += EXP2(fmaf(x, EXPC, -EXPC));  // single v_exp_f32
      unsigned ky = (__float_as_uint(x + 2.0f) & 0xFFFFE000u) | colu;  // x+2>0: monotone
      key[r] = ky > key[r] ? ky : key[r];
    }
    colu += NSPL*32;
    p = pn;
  }
  { // last chunk, no prefetch
    f32x16 acc = {};
    #pragma unroll
    for (int k=0;k<8;k++)
      acc = __builtin_amdgcn_mfma_f32_32x32x16_f16(a[k], b0[k], acc, 0,0,0);
    #pragma unroll
    for (int k=0;k<8;k++)
      acc = __builtin_amdgcn_mfma_f32_32x32x16_f16(a[k+8], b1[k], acc, 0,0,0);
    #pragma unroll
    for (int r=0;r<16;r++) {
      float x = acc[r];
      ssum[r] += EXP2(fmaf(x, EXPC, -EXPC));
      unsigned ky = (__float_as_uint(x + 2.0f) & 0xFFFFE000u) | colu;
      key[r] = ky > key[r] ? ky : key[r];
    }
  }

  // reduce across the 32 lanes (cols); offsets 1..16 stay within each half
  #pragma unroll
  for (int off=1; off<32; off<<=1) {
    #pragma unroll
    for (int r=0;r<16;r++) {
      ssum[r] += __shfl_xor(ssum[r], off);
      unsigned o = __shfl_xor(key[r], off);
      key[r] = o > key[r] ? o : key[r];
    }
  }
  if (l31 == 0) {
    const int rowbase = tile*32;
    #pragma unroll
    for (int r=0;r<16;r++) {
      int row = rowbase + (r&3) + 8*(r>>2) + 4*lh;
      psum[split*B_ROWS + row] = ssum[r];
      pkey[split*B_ROWS + row] = key[r];
    }
  }
}

// ---------------- tail: das + merge + finalize (completion counter) ------
__global__ __launch_bounds__(256)
void k_tail(const float* __restrict__ emb, const float* __restrict__ W,
            const int* __restrict__ y, const int* __restrict__ y_d,
            const float* __restrict__ rne, const float* __restrict__ rnw,
            const float* __restrict__ psum, const unsigned* __restrict__ pkey,
            float* __restrict__ accum, float* __restrict__ out) {
  __shared__ float s0[4], s1[4];
  const int wid = threadIdx.x >> 6, lane = threadIdx.x & 63;
  if (blockIdx.x < 128) {
    // ----- merge: per-row exact y-logit + combine partials -----
    float lacc = 0.f, cacc = 0.f;
    for (int row = blockIdx.x*4 + wid; row < B_ROWS; row += 512) {
      const int yc = y[row];
      float4 e = *(const float4*)(emb + (size_t)row*DIM + lane*4);
      float4 w = *(const float4*)(W + (size_t)yc*DIM + lane*4);
      float d = e.x*w.x + e.y*w.y + e.z*w.z + e.w*w.w;
      #pragma unroll
      for (int off=1; off<64; off<<=1) d += __shfl_xor(d, off);
      float S = 0.f; unsigned km = 0u;
      if (lane < NSPL) {
        S = psum[lane*B_ROWS + row];
        km = pkey[lane*B_ROWS + row];
      }
      #pragma unroll
      for (int off=1; off<NSPL; off<<=1) {
        S += __shfl_xor(S, off);
        unsigned o = __shfl_xor(km, off);
        if (o > km) km = o;
      }
      if (lane == 0) {
        float ly = SCALE_F * d * rne[row] * rnw[yc];
        lacc += MAXL + logf(S) - ly;
        cacc += ((km & 0x1FFFu) == (unsigned)yc) ? 1.f : 0.f;
      }
    }
    if (lane == 0) { s0[wid] = lacc; s1[wid] = cacc; }
    __syncthreads();
    if (threadIdx.x == 0) {
      atomicAdd(&accum[0], s0[0]+s0[1]+s0[2]+s0[3]);
      atomicAdd(&accum[1], s1[0]+s1[1]+s1[2]+s1[3]);
    }
  } else {
    // ----- das: contrastive pair distances (f32, from raw emb) -----
    float a2 = 0.f, a3 = 0.f;
    for (int i = (blockIdx.x-128)*4 + wid; i < H_HALF; i += 256) {
      const int j = (i+1) & (H_HALF-1);
      const int di = y_d[i], dj = y_d[j], dih = y_d[i + H_HALF];
      float4 z = {0.f,0.f,0.f,0.f};
      float4 mi = (di==0)  ? *(const float4*)(emb + (size_t)i*DIM + lane*4) : z;
      float4 mj = (dj==0)  ? *(const float4*)(emb + (size_t)j*DIM + lane*4) : z;
      float4 ti = (dih!=0) ? *(const float4*)(emb + (size_t)(i+H_HALF)*DIM + lane*4)
                           : ((di!=0) ? *(const float4*)(emb + (size_t)i*DIM + lane*4) : z);
      float px = mi.x-mj.x, py = mi.y-mj.y, pz = mi.z-mj.z, pw = mi.w-mj.w;
      float nx = mi.x-ti.x, ny = mi.y-ti.y, nz = mi.z-ti.z, nw = mi.w-ti.w;
      float sp = px*px+py*py+pz*pz+pw*pw;
      float sn = nx*nx+ny*ny+nz*nz+nw*nw;
      #pragma unroll
      for (int off=1; off<64; off<<=1) { sp += __shfl_xor(sp, off); sn += __shfl_xor(sn, off); }
      if (lane == 0) {
        float dp = sqrtf(sp), dn = sqrtf(sn);
        float m = fmaxf(2.0f - dp, 0.f);
        a2 += m*m + dn*dn;
        a3 += dp + dn;
      }
    }
    if (lane == 0) { s0[wid] = a2; s1[wid] = a3; }
    __syncthreads();
    if (threadIdx.x == 0) {
      atomicAdd(&accum[2], s0[0]+s0[1]+s0[2]+s0[3]);
      atomicAdd(&accum[3], s1[0]+s1[1]+s1[2]+s1[3]);
    }
  }
  // ----- finalize: last block to finish writes the 4 outputs -----
  if (threadIdx.x == 0) {
    __threadfence();                                   // publish accum adds
    unsigned* cnt = (unsigned*)(accum + 4);
    unsigned done = atomicAdd(cnt, 1u);
    if (done == 191u) {                                // last of 192 blocks
      float v0 = atomicAdd(&accum[0], 0.f);            // coherent reads
      float v1 = atomicAdd(&accum[1], 0.f);
      float v2 = atomicAdd(&accum[2], 0.f);
      float v3 = atomicAdd(&accum[3], 0.f);
      out[0] = v0 * (1.0f/B_ROWS);  // loss_c
      out[1] = v2 * (1.0f/B_ROWS);  // das_loss
      out[2] = v1 * (1.0f/B_ROWS);  // acc
      out[3] = v3 * (1.0f/B_ROWS);  // das_dist_mean
    }
  }
}

extern "C" void kernel_launch(void* const* d_in, const int* in_sizes, int n_in,
                              void* d_out, int out_size, void* d_ws, size_t ws_size,
                              hipStream_t stream) {
  const float* emb = (const float*)d_in[0];
  const float* W   = (const float*)d_in[1];
  const int*   y   = (const int*)d_in[2];
  const int*   y_d = (const int*)d_in[3];

  char* ws = (char*)d_ws;
  const size_t EN_OFF   = 0;                                  // 256 tiles * 16 KB = 4,194,304
  const size_t WN_OFF   = EN_OFF  + (size_t)256*16384;        // 188 tiles * 16 KB = 3,080,192
  const size_t RNE_OFF  = WN_OFF  + (size_t)N_CHUNK*16384;    // 32,768
  const size_t RNW_OFF  = RNE_OFF + (size_t)B_ROWS*4;         // 24,064 (6016 floats)
  const size_t PSUM_OFF = RNW_OFF + 24064;                    // 16*8192*4 = 524,288
  const size_t PKEY_OFF = PSUM_OFF + (size_t)NSPL*B_ROWS*4;   // 16*8192*4 = 524,288
  const size_t ACC_OFF  = PKEY_OFF + (size_t)NSPL*B_ROWS*4;   // 32 (4 floats + cnt + pad)

  _Float16* en_blk = (_Float16*)(ws + EN_OFF);
  _Float16* wn_blk = (_Float16*)(ws + WN_OFF);
  float*    rne   = (float*)(ws + RNE_OFF);
  float*    rnw   = (float*)(ws + RNW_OFF);
  float*    psum  = (float*)(ws + PSUM_OFF);
  unsigned* pkey  = (unsigned*)(ws + PKEY_OFF);
  float*    accum = (float*)(ws + ACC_OFF);

  k_pack<<<B_ROWS/32 + N_CHUNK, 256, 0, stream>>>(emb, W, en_blk, wn_blk, rne, rnw, accum);
  k_logits<<<64*NSPL, 256, 0, stream>>>(en_blk, wn_blk, psum, pkey);
  k_tail<<<192, 256, 0, stream>>>(emb, W, y, y_d, rne, rnw, psum, pkey, accum, (float*)d_out);
}

// Round 12
// 67.472 us; speedup vs baseline: 2.3075x; 1.1527x over previous
//
#include <hip/hip_runtime.h>
#include <hip/hip_bf16.h>

#define B_ROWS 8192
#define DIM 256
#define C_CLS 5994
#define N_CHUNK 188       // 6016 / 32
#define NSPL 16
#define H_HALF 4096
#define SCALE_F 30.0f
#define MAXL 30.0f
#define EXPC 43.2808512266689f   // 30*log2(e):  exp(30x-30) = exp2(EXPC*x - EXPC)

#if defined(__has_builtin)
#if __has_builtin(__builtin_amdgcn_exp2f)
#define EXP2(x) __builtin_amdgcn_exp2f(x)
#endif
#endif
#ifndef EXP2
#define EXP2(x) exp2f(x)
#endif

typedef float f32x16 __attribute__((ext_vector_type(16)));
typedef long long ll;
typedef ll ll2 __attribute__((ext_vector_type(2)));

// ---------------- pack: norms + blocked FP8 layouts + accum zero ---------
// FP8 blocked layout per 32-row tile (8 KB), PAIRED frags so loads stay 16B:
// pair j (=frags 2j,2j+1, k in [32j,32j+32)): byte = j*1024 + (h*32+row)*16 + slot*8 + idx
// where h = k-half within frag, slot = frag within pair. A wave's paired-frag
// load is lane-linear: base + j*1024 + lane*16 -> one contiguous 1 KB load.
__global__ __launch_bounds__(256)
void k_pack(const float* __restrict__ emb, const float* __restrict__ W,
            char* __restrict__ en_blk, char* __restrict__ wn_blk,
            float* __restrict__ rne, float* __restrict__ rnw,
            float* __restrict__ accum) {
  __shared__ float ssm[256];
  __shared__ float rnl[32];
  const int b = blockIdx.x;
  const int t = threadIdx.x;
  if (b == 0 && t < 8) accum[t] = 0.f;   // accum[0..3] + counter(+pad), zeroed every call
  const bool isW = b >= (B_ROWS/32);
  const int tile = isW ? b - (B_ROWS/32) : b;
  const int l31 = t & 31;
  const int row = tile*32 + l31;
  const float* __restrict__ src = isW ? W : emb;
  const bool rv = (!isW) || (row < C_CLS);

  float v[4][8];
  float ss = 0.f;
  #pragma unroll
  for (int i=0;i<4;i++) {
    const int d0 = ((t>>6) + i*4)*16 + ((t>>5)&1)*8;
    if (rv) {
      float4 x0 = *(const float4*)(src + (size_t)row*DIM + d0);
      float4 x1 = *(const float4*)(src + (size_t)row*DIM + d0 + 4);
      v[i][0]=x0.x; v[i][1]=x0.y; v[i][2]=x0.z; v[i][3]=x0.w;
      v[i][4]=x1.x; v[i][5]=x1.y; v[i][6]=x1.z; v[i][7]=x1.w;
      ss += x0.x*x0.x + x0.y*x0.y + x0.z*x0.z + x0.w*x0.w
          + x1.x*x1.x + x1.y*x1.y + x1.z*x1.z + x1.w*x1.w;
    } else {
      #pragma unroll
      for (int j=0;j<8;j++) v[i][j] = 0.f;
    }
  }
  ssm[t] = ss;
  __syncthreads();
  if (t < 32) {
    float s = 0.f;
    #pragma unroll
    for (int j=0;j<8;j++) s += ssm[t + j*32];
    float rn = 1.0f/(sqrtf(s) + 1e-12f);
    rnl[t] = rn;
    int rw = tile*32 + t;
    if (!isW) rne[rw] = rn;
    else if (rw < C_CLS) rnw[rw] = rn;
  }
  __syncthreads();
  const float rn = rnl[l31];
  char* __restrict__ dst = (isW ? wn_blk : en_blk) + (size_t)tile*8192;
  const int kbase = (t>>5)*512 + l31*16;  // ((t>>5)&1)*512? no: h=(t>>5)&1 below
  (void)kbase;
  #pragma unroll
  for (int i=0;i<4;i++) {
    const int kk = (t>>6) + i*4;
    const int off = (kk>>1)*1024 + ((t>>5)&1)*512 + l31*16 + (kk&1)*8;
    int d0 = 0, d1 = 0;
    d0 = __builtin_amdgcn_cvt_pk_fp8_f32(v[i][0]*rn, v[i][1]*rn, d0, false);
    d0 = __builtin_amdgcn_cvt_pk_fp8_f32(v[i][2]*rn, v[i][3]*rn, d0, true);
    d1 = __builtin_amdgcn_cvt_pk_fp8_f32(v[i][4]*rn, v[i][5]*rn, d1, false);
    d1 = __builtin_amdgcn_cvt_pk_fp8_f32(v[i][6]*rn, v[i][7]*rn, d1, true);
    uint2 u; u.x = (unsigned)d0; u.y = (unsigned)d1;
    *(uint2*)(dst + off) = u;              // 8B store, stride-16 pattern (pack-only cost)
  }
}

// ---------------- main fused GEMM + online softmax-stats (FP8) ----------
// grid = 64 panels x 16 splits = 1024 blocks (4/CU); block = 256 (4 waves).
// Barrier-free; B register-double-buffered (4-pair halves); peeled last iter.
// fp8 halves L1 operand bytes vs f16: per-CU L1 ~1.7 MB (~11 us) vs 3.3 MB.
__global__ __launch_bounds__(256, 2)
void k_logits(const char* __restrict__ en_blk, const char* __restrict__ wn_blk,
              float* __restrict__ psum, unsigned* __restrict__ pkey) {
  const int split = blockIdx.x & (NSPL-1);
  const int panel = blockIdx.x / NSPL;
  const int wid  = threadIdx.x >> 6;
  const int lane = threadIdx.x & 63;
  const int l31  = lane & 31;
  const int lh   = lane >> 5;
  const int tile = panel*4 + wid;
  (void)lh;

  // A paired-frags: 8 contiguous 1 KB wave-loads, resident all loop
  ll2 a[8];
  const char* ab = en_blk + (size_t)tile*8192 + lane*16;
  #pragma unroll
  for (int j=0;j<8;j++) a[j] = *(const ll2*)(ab + j*1024);

  float ssum[16]; unsigned key[16];
  #pragma unroll
  for (int r=0;r<16;r++){ ssum[r]=0.f; key[r]=0u; }

  const int nit = (N_CHUNK - split + NSPL - 1) / NSPL;   // 12 or 11
  const char* p = wn_blk + (size_t)split*8192 + lane*16;
  const ptrdiff_t STEP = (ptrdiff_t)NSPL*8192;

  ll2 b0[4], b1[4];
  #pragma unroll
  for (int j=0;j<4;j++) b0[j] = *(const ll2*)(p + j*1024);
  #pragma unroll
  for (int j=0;j<4;j++) b1[j] = *(const ll2*)(p + (j+4)*1024);

  unsigned colu = (unsigned)(split*32 + l31);
  for (int it = 0; it < nit-1; ++it) {
    const char* pn = p + STEP;
    f32x16 acc = {};
    #pragma unroll
    for (int j=0;j<4;j++) {
      acc = __builtin_amdgcn_mfma_f32_32x32x16_fp8_fp8(a[j][0], b0[j][0], acc, 0,0,0);
      acc = __builtin_amdgcn_mfma_f32_32x32x16_fp8_fp8(a[j][1], b0[j][1], acc, 0,0,0);
    }
    #pragma unroll
    for (int j=0;j<4;j++) b0[j] = *(const ll2*)(pn + j*1024);
    #pragma unroll
    for (int j=0;j<4;j++) {
      acc = __builtin_amdgcn_mfma_f32_32x32x16_fp8_fp8(a[j+4][0], b1[j][0], acc, 0,0,0);
      acc = __builtin_amdgcn_mfma_f32_32x32x16_fp8_fp8(a[j+4][1], b1[j][1], acc, 0,0,0);
    }
    #pragma unroll
    for (int j=0;j<4;j++) b1[j] = *(const ll2*)(pn + (j+4)*1024);
    // epilogue: pad cols are zero rows -> x=0 -> exp2(-43.3)~1e-13, negligible
    #pragma unroll
    for (int r=0;r<16;r++) {
      float x = acc[r];                       // cosine in [-1,1] (+fp8 noise)
      ssum[r] += EXP2(fmaf(x, EXPC, -EXPC));  // single v_exp_f32
      unsigned ky = (__float_as_uint(x + 2.0f) & 0xFFFFE000u) | colu;  // x+2>0: monotone
      key[r] = ky > key[r] ? ky : key[r];
    }
    colu += NSPL*32;
    p = pn;
  }
  { // last chunk, no prefetch
    f32x16 acc = {};
    #pragma unroll
    for (int j=0;j<4;j++) {
      acc = __builtin_amdgcn_mfma_f32_32x32x16_fp8_fp8(a[j][0], b0[j][0], acc, 0,0,0);
      acc = __builtin_amdgcn_mfma_f32_32x32x16_fp8_fp8(a[j][1], b0[j][1], acc, 0,0,0);
    }
    #pragma unroll
    for (int j=0;j<4;j++) {
      acc = __builtin_amdgcn_mfma_f32_32x32x16_fp8_fp8(a[j+4][0], b1[j][0], acc, 0,0,0);
      acc = __builtin_amdgcn_mfma_f32_32x32x16_fp8_fp8(a[j+4][1], b1[j][1], acc, 0,0,0);
    }
    #pragma unroll
    for (int r=0;r<16;r++) {
      float x = acc[r];
      ssum[r] += EXP2(fmaf(x, EXPC, -EXPC));
      unsigned ky = (__float_as_uint(x + 2.0f) & 0xFFFFE000u) | colu;
      key[r] = ky > key[r] ? ky : key[r];
    }
  }

  // reduce across the 32 lanes (cols); offsets 1..16 stay within each half
  #pragma unroll
  for (int off=1; off<32; off<<=1) {
    #pragma unroll
    for (int r=0;r<16;r++) {
      ssum[r] += __shfl_xor(ssum[r], off);
      unsigned o = __shfl_xor(key[r], off);
      key[r] = o > key[r] ? o : key[r];
    }
  }
  if (l31 == 0) {
    const int rowbase = tile*32;
    #pragma unroll
    for (int r=0;r<16;r++) {
      int row = rowbase + (r&3) + 8*(r>>2) + 4*(lane>>5);
      psum[split*B_ROWS + row] = ssum[r];
      pkey[split*B_ROWS + row] = key[r];
    }
  }
}

// ---------------- tail: das + merge + finalize (completion counter) ------
__global__ __launch_bounds__(256)
void k_tail(const float* __restrict__ emb, const float* __restrict__ W,
            const int* __restrict__ y, const int* __restrict__ y_d,
            const float* __restrict__ rne, const float* __restrict__ rnw,
            const float* __restrict__ psum, const unsigned* __restrict__ pkey,
            float* __restrict__ accum, float* __restrict__ out) {
  __shared__ float s0[4], s1[4];
  const int wid = threadIdx.x >> 6, lane = threadIdx.x & 63;
  if (blockIdx.x < 128) {
    // ----- merge: per-row exact y-logit + combine partials -----
    float lacc = 0.f, cacc = 0.f;
    for (int row = blockIdx.x*4 + wid; row < B_ROWS; row += 512) {
      const int yc = y[row];
      float4 e = *(const float4*)(emb + (size_t)row*DIM + lane*4);
      float4 w = *(const float4*)(W + (size_t)yc*DIM + lane*4);
      float d = e.x*w.x + e.y*w.y + e.z*w.z + e.w*w.w;
      #pragma unroll
      for (int off=1; off<64; off<<=1) d += __shfl_xor(d, off);
      float S = 0.f; unsigned km = 0u;
      if (lane < NSPL) {
        S = psum[lane*B_ROWS + row];
        km = pkey[lane*B_ROWS + row];
      }
      #pragma unroll
      for (int off=1; off<NSPL; off<<=1) {
        S += __shfl_xor(S, off);
        unsigned o = __shfl_xor(km, off);
        if (o > km) km = o;
      }
      if (lane == 0) {
        float ly = SCALE_F * d * rne[row] * rnw[yc];
        lacc += MAXL + logf(S) - ly;
        cacc += ((km & 0x1FFFu) == (unsigned)yc) ? 1.f : 0.f;
      }
    }
    if (lane == 0) { s0[wid] = lacc; s1[wid] = cacc; }
    __syncthreads();
    if (threadIdx.x == 0) {
      atomicAdd(&accum[0], s0[0]+s0[1]+s0[2]+s0[3]);
      atomicAdd(&accum[1], s1[0]+s1[1]+s1[2]+s1[3]);
    }
  } else {
    // ----- das: contrastive pair distances (f32, from raw emb) -----
    float a2 = 0.f, a3 = 0.f;
    for (int i = (blockIdx.x-128)*4 + wid; i < H_HALF; i += 256) {
      const int j = (i+1) & (H_HALF-1);
      const int di = y_d[i], dj = y_d[j], dih = y_d[i + H_HALF];
      float4 z = {0.f,0.f,0.f,0.f};
      float4 mi = (di==0)  ? *(const float4*)(emb + (size_t)i*DIM + lane*4) : z;
      float4 mj = (dj==0)  ? *(const float4*)(emb + (size_t)j*DIM + lane*4) : z;
      float4 ti = (dih!=0) ? *(const float4*)(emb + (size_t)(i+H_HALF)*DIM + lane*4)
                           : ((di!=0) ? *(const float4*)(emb + (size_t)i*DIM + lane*4) : z);
      float px = mi.x-mj.x, py = mi.y-mj.y, pz = mi.z-mj.z, pw = mi.w-mj.w;
      float nx = mi.x-ti.x, ny = mi.y-ti.y, nz = mi.z-ti.z, nw = mi.w-ti.w;
      float sp = px*px+py*py+pz*pz+pw*pw;
      float sn = nx*nx+ny*ny+nz*nz+nw*nw;
      #pragma unroll
      for (int off=1; off<64; off<<=1) { sp += __shfl_xor(sp, off); sn += __shfl_xor(sn, off); }
      if (lane == 0) {
        float dp = sqrtf(sp), dn = sqrtf(sn);
        float m = fmaxf(2.0f - dp, 0.f);
        a2 += m*m + dn*dn;
        a3 += dp + dn;
      }
    }
    if (lane == 0) { s0[wid] = a2; s1[wid] = a3; }
    __syncthreads();
    if (threadIdx.x == 0) {
      atomicAdd(&accum[2], s0[0]+s0[1]+s0[2]+s0[3]);
      atomicAdd(&accum[3], s1[0]+s1[1]+s1[2]+s1[3]);
    }
  }
  // ----- finalize: last block to finish writes the 4 outputs -----
  if (threadIdx.x == 0) {
    __threadfence();                                   // publish accum adds
    unsigned* cnt = (unsigned*)(accum + 4);
    unsigned done = atomicAdd(cnt, 1u);
    if (done == 191u) {                                // last of 192 blocks
      float v0 = atomicAdd(&accum[0], 0.f);            // coherent reads
      float v1 = atomicAdd(&accum[1], 0.f);
      float v2 = atomicAdd(&accum[2], 0.f);
      float v3 = atomicAdd(&accum[3], 0.f);
      out[0] = v0 * (1.0f/B_ROWS);  // loss_c
      out[1] = v2 * (1.0f/B_ROWS);  // das_loss
      out[2] = v1 * (1.0f/B_ROWS);  // acc
      out[3] = v3 * (1.0f/B_ROWS);  // das_dist_mean
    }
  }
}

extern "C" void kernel_launch(void* const* d_in, const int* in_sizes, int n_in,
                              void* d_out, int out_size, void* d_ws, size_t ws_size,
                              hipStream_t stream) {
  const float* emb = (const float*)d_in[0];
  const float* W   = (const float*)d_in[1];
  const int*   y   = (const int*)d_in[2];
  const int*   y_d = (const int*)d_in[3];

  char* ws = (char*)d_ws;
  const size_t EN_OFF   = 0;                                  // 256 tiles * 8 KB = 2,097,152
  const size_t WN_OFF   = EN_OFF  + (size_t)256*8192;         // 188 tiles * 8 KB = 1,540,096
  const size_t RNE_OFF  = WN_OFF  + (size_t)N_CHUNK*8192;     // 32,768
  const size_t RNW_OFF  = RNE_OFF + (size_t)B_ROWS*4;         // 24,064 (6016 floats)
  const size_t PSUM_OFF = RNW_OFF + 24064;                    // 16*8192*4 = 524,288
  const size_t PKEY_OFF = PSUM_OFF + (size_t)NSPL*B_ROWS*4;   // 16*8192*4 = 524,288
  const size_t ACC_OFF  = PKEY_OFF + (size_t)NSPL*B_ROWS*4;   // 32 (4 floats + cnt + pad)

  char*     en_blk = ws + EN_OFF;
  char*     wn_blk = ws + WN_OFF;
  float*    rne   = (float*)(ws + RNE_OFF);
  float*    rnw   = (float*)(ws + RNW_OFF);
  float*    psum  = (float*)(ws + PSUM_OFF);
  unsigned* pkey  = (unsigned*)(ws + PKEY_OFF);
  float*    accum = (float*)(ws + ACC_OFF);

  k_pack<<<B_ROWS/32 + N_CHUNK, 256, 0, stream>>>(emb, W, en_blk, wn_blk, rne, rnw, accum);
  k_logits<<<64*NSPL, 256, 0, stream>>>(en_blk, wn_blk, psum, pkey);
  k_tail<<<192, 256, 0, stream>>>(emb, W, y, y_d, rne, rnw, psum, pkey, accum, (float*)d_out);
}